// Round 1
// 23262.935 us; speedup vs baseline: 1.0973x; 1.0973x over previous
//
#include <hip/hip_runtime.h>

static constexpr int kB = 128, kS = 512, kH = 768;

typedef __attribute__((ext_vector_type(8))) short short8;
typedef __attribute__((ext_vector_type(4))) float f32x4;

__device__ __forceinline__ unsigned short f2bf(float x) {
  unsigned u = __float_as_uint(x);
  u += 0x7fffu + ((u >> 16) & 1u);   // RNE
  return (unsigned short)(u >> 16);
}
__device__ __forceinline__ float bf2f(unsigned short h) {
  return __uint_as_float(((unsigned)h) << 16);
}
__device__ __forceinline__ short8 pack_bf8(const float* __restrict__ p) {
  short8 r;
#pragma unroll
  for (int i = 0; i < 8; ++i) r[i] = (short)f2bf(p[i]);
  return r;
}
__device__ __forceinline__ float fsigm(float x) {
  return __builtin_amdgcn_rcpf(1.0f + __expf(-x));
}
__device__ __forceinline__ float ftanh(float x) {
  return 1.0f - 2.0f * __builtin_amdgcn_rcpf(1.0f + __expf(2.0f * x));
}

// ---------------- fp32 -> bf16 cast (layout-preserving) ----------------
__global__ __launch_bounds__(256) void cast_bf16_kernel(const float* __restrict__ src,
                                                        unsigned short* __restrict__ dst,
                                                        int n) {
  int i = (blockIdx.x * 256 + threadIdx.x) * 4;
  if (i < n) {
    float4 v = *(const float4*)(src + i);
    *(ushort4*)(dst + i) = make_ushort4(f2bf(v.x), f2bf(v.y), f2bf(v.z), f2bf(v.w));
  }
}

// ---------------- fp32 [B][S][H] -> bf16 time-major [S][B][H] ----------------
__global__ __launch_bounds__(192) void cast_tr_kernel(const float* __restrict__ src,
                                                      unsigned short* __restrict__ dst) {
  const int bs = blockIdx.x;            // b*kS + s
  const int b = bs >> 9, s = bs & (kS - 1);
  const int i = threadIdx.x * 4;
  float4 v = *(const float4*)(src + (size_t)bs * kH + i);
  *(ushort4*)(dst + ((size_t)s * kB + b) * kH + i) =
      make_ushort4(f2bf(v.x), f2bf(v.y), f2bf(v.z), f2bf(v.w));
}

// ---------------- diagnostic canary: pre-fill ys ----------------
__global__ __launch_bounds__(256) void fill_kernel(float* __restrict__ p, int n) {
  int i = (blockIdx.x * 256 + threadIdx.x) * 4;
  if (i < n) *(float4*)(p + i) = make_float4(100.f, 100.f, 100.f, 100.f);
}

// ---------------- device-scope group barrier (distributed flags) ----------------
// Each of the 48 blocks in a group owns one 64B-spaced flag slot; arrival is a
// parallel relaxed-agent store (no serialized RMW). Wave 0 polls all 48 flags
// with one lane each. Fences preserve the proven release/acquire semantics.
__device__ __forceinline__ void group_barrier(unsigned* flags, int sid, unsigned target,
                                              int w, int lane) {
  __syncthreads();                                      // all waves' stores issued
  __builtin_amdgcn_fence(__ATOMIC_RELEASE, "agent");    // L2 writeback -> cross-XCD visible
  if (threadIdx.x == 0)
    __hip_atomic_store(flags + sid * 16, target, __ATOMIC_RELAXED, __HIP_MEMORY_SCOPE_AGENT);
  if (w == 0) {
    const unsigned* p = flags + (lane < 48 ? lane : 0) * 16;
    for (;;) {
      unsigned v = __hip_atomic_load(p, __ATOMIC_RELAXED, __HIP_MEMORY_SCOPE_AGENT);
      if (__all(v >= target)) break;
      __builtin_amdgcn_s_sleep(1);
    }
  }
  __syncthreads();
  __builtin_amdgcn_fence(__ATOMIC_ACQUIRE, "agent");    // invalidate stale L1/L2
}

// ---------------- the scan ----------------
// 192 blocks: g = bid&3 -> batch rows [g*32, +32); stripe = bid>>2 -> hidden cols [stripe*16, +16)
// wave w = gate w (f,i,o,c~) over 2 M-tiles; waves 0,1 additionally do the W_d GEMM
// for M-tile w. Weight B-frags are VGPR-resident (fully unrolled kk loop).
// h/c exchanged through global bf16 ping-pong buffers; c master copy is fp32 in LDS.
__global__ __launch_bounds__(256, 1) void scan_kernel(
    const unsigned short* __restrict__ Xb, unsigned short* __restrict__ hbuf,
    unsigned short* __restrict__ cbuf, const float* __restrict__ Wall,
    const float* __restrict__ Wallb, const float* __restrict__ Uall,
    const float* __restrict__ Uallb, const float* __restrict__ Wd,
    const float* __restrict__ Wdb, const float* __restrict__ ts,
    const float* __restrict__ c0, float* __restrict__ ys, unsigned* bar) {
  __shared__ float lds_pre[4][32][16];
  __shared__ float lds_d[32][16];
  __shared__ float lds_cm[32][16];

  const int t = threadIdx.x;
  const int w = t >> 6, lane = t & 63, l15 = lane & 15, lhi = lane >> 4;
  const int g = blockIdx.x & 3, stripe = blockIdx.x >> 2;
  const int b0 = g * 32, j0 = stripe * 16;
  unsigned* flags = bar + (size_t)g * 48 * 16;  // 48 slots, 64B apart, per group

  // step-invariant weights -> registers. B-frag: n=l15 (output col), k=lhi*8+j
  // FULLY unrolled so wg/ug/wdv are VGPR-resident (runtime indexing => scratch).
  short8 wg[24], ug[24], wdv[24];
#pragma unroll
  for (int kk = 0; kk < 24; ++kk) {
    const float* wrow = Wall + (size_t)(w * kH + j0 + l15) * kH + kk * 32 + lhi * 8;
    const float* urow = Uall + (size_t)(w * kH + j0 + l15) * kH + kk * 32 + lhi * 8;
    wg[kk] = pack_bf8(wrow);
    ug[kk] = pack_bf8(urow);
  }
  const bool do_c = (w < 2);
  if (do_c) {
#pragma unroll
    for (int kk = 0; kk < 24; ++kk) {
      const float* drow = Wd + (size_t)(j0 + l15) * kH + kk * 32 + lhi * 8;
      wdv[kk] = pack_bf8(drow);
    }
  }

  // elementwise mapping: 32 rows x 8 thread-cols x 2 elems
  const int erow = t >> 3, eq = t & 7;
  const int eb = b0 + erow, jc = j0 + eq * 2;
  {
    float2 v = *(const float2*)(c0 + (size_t)eb * kH + jc);
    lds_cm[erow][eq * 2 + 0] = v.x;
    lds_cm[erow][eq * 2 + 1] = v.y;
  }
  float bsum[4][2], bd[2];
#pragma unroll
  for (int gg = 0; gg < 4; ++gg)
#pragma unroll
    for (int u = 0; u < 2; ++u) bsum[gg][u] = Wallb[gg * kH + jc + u] + Uallb[gg * kH + jc + u];
#pragma unroll
  for (int u = 0; u < 2; ++u) bd[u] = Wdb[jc + u];

  int hoff[2], xoff[2];
#pragma unroll
  for (int mt = 0; mt < 2; ++mt) {
    hoff[mt] = (b0 + mt * 16 + l15) * kH + lhi * 8;
    xoff[mt] = (b0 + mt * 16 + l15) * kH + lhi * 8;  // within time-major slab
  }
  const int coff = (b0 + (w & 1) * 16 + l15) * kH + lhi * 8;

  const float* tsrow = ts + (size_t)eb * kS;
  const size_t yrow = (size_t)eb * kS * kH + jc;

#pragma unroll 1
  for (int s = 0; s < kS; ++s) {
    const unsigned short* hb = hbuf + (s & 1) * (kB * kH);
    const unsigned short* cb = cbuf + (s & 1) * (kB * kH);
    unsigned short* hbn = hbuf + ((s + 1) & 1) * (kB * kH);
    unsigned short* cbn = cbuf + ((s + 1) & 1) * (kB * kH);
    const unsigned short* xs = Xb + (size_t)s * (kB * kH);  // contiguous 196KB slab

    const float tv = tsrow[s];  // issue early; overlaps MFMA loop

    // 5 independent accumulator chains for ILP
    f32x4 aw0 = {0.f, 0.f, 0.f, 0.f}, au0 = aw0, aw1 = aw0, au1 = aw0, ad = aw0;
#pragma unroll
    for (int kk = 0; kk < 24; ++kk) {
      const int o = kk * 32;
      short8 hf0 = *(const short8*)(hb + hoff[0] + o);
      aw0 = __builtin_amdgcn_mfma_f32_16x16x32_bf16(hf0, wg[kk], aw0, 0, 0, 0);
      short8 xf0 = *(const short8*)(xs + xoff[0] + o);
      au0 = __builtin_amdgcn_mfma_f32_16x16x32_bf16(xf0, ug[kk], au0, 0, 0, 0);
      short8 hf1 = *(const short8*)(hb + hoff[1] + o);
      aw1 = __builtin_amdgcn_mfma_f32_16x16x32_bf16(hf1, wg[kk], aw1, 0, 0, 0);
      short8 xf1 = *(const short8*)(xs + xoff[1] + o);
      au1 = __builtin_amdgcn_mfma_f32_16x16x32_bf16(xf1, ug[kk], au1, 0, 0, 0);
      if (do_c) {
        short8 cf = *(const short8*)(cb + coff + o);
        ad = __builtin_amdgcn_mfma_f32_16x16x32_bf16(cf, wdv[kk], ad, 0, 0, 0);
      }
    }
    // C/D layout: row = lhi*4+r, col = l15
#pragma unroll
    for (int r = 0; r < 4; ++r) {
      lds_pre[w][0 + lhi * 4 + r][l15] = aw0[r] + au0[r];
      lds_pre[w][16 + lhi * 4 + r][l15] = aw1[r] + au1[r];
    }
    if (do_c) {
#pragma unroll
      for (int r = 0; r < 4; ++r) lds_d[w * 16 + lhi * 4 + r][l15] = ad[r];
    }
    __syncthreads();

    float hn[2], cn[2];
#pragma unroll
    for (int u = 0; u < 2; ++u) {
      const int jj = eq * 2 + u;
      float cs1 = ftanh(lds_d[erow][jj] + bd[u]);
      float cold = lds_cm[erow][jj];
      float cadj = cold + cs1 * (tv - 1.0f);  // (c - cs1) + cs1*t
      float fv = fsigm(lds_pre[0][erow][jj] + bsum[0][u]);
      float iv = fsigm(lds_pre[1][erow][jj] + bsum[1][u]);
      float ov = fsigm(lds_pre[2][erow][jj] + bsum[2][u]);
      float cv = fsigm(lds_pre[3][erow][jj] + bsum[3][u]);
      float cnew = fv * cadj + iv * cv;
      float hnew = ov * ftanh(cnew);
      lds_cm[erow][jj] = cnew;
      hn[u] = hnew;
      cn[u] = cnew;
    }
    *(float2*)(ys + yrow + (size_t)s * kH) = make_float2(hn[0], hn[1]);
    *(ushort2*)(hbn + eb * kH + jc) = make_ushort2(f2bf(hn[0]), f2bf(hn[1]));
    *(ushort2*)(cbn + eb * kH + jc) = make_ushort2(f2bf(cn[0]), f2bf(cn[1]));

    if (s != kS - 1) group_barrier(flags, stripe, (unsigned)(s + 1), w, lane);
  }
}

extern "C" void kernel_launch(void* const* d_in, const int* in_sizes, int n_in,
                              void* d_out, int out_size, void* d_ws, size_t ws_size,
                              hipStream_t stream) {
  const float* inputs = (const float*)d_in[0];
  const float* tsp    = (const float*)d_in[1];
  const float* h0     = (const float*)d_in[2];
  const float* c0     = (const float*)d_in[3];
  const float* Wall   = (const float*)d_in[4];
  const float* Wallb  = (const float*)d_in[5];
  const float* Uall   = (const float*)d_in[6];
  const float* Uallb  = (const float*)d_in[7];
  const float* Wd     = (const float*)d_in[8];
  const float* Wdb    = (const float*)d_in[9];
  float* ys = (float*)d_out;

  char* ws = (char*)d_ws;
  unsigned* bar        = (unsigned*)(ws);                 // 16 KB (4 groups x 48 flags, 64B apart)
  unsigned short* hbuf = (unsigned short*)(ws + 16384);   // 393,216 B (ping-pong)
  unsigned short* cbuf = (unsigned short*)(ws + 409600);  // 393,216 B (ping-pong)
  unsigned short* Xb   = (unsigned short*)(ws + 802816);  // 100,663,296 B (time-major)

  hipMemsetAsync(bar, 0, 16384, stream);
  cast_tr_kernel<<<kB * kS, 192, 0, stream>>>(inputs, Xb);
  cast_bf16_kernel<<<96, 256, 0, stream>>>(h0, hbuf, kB * kH);
  cast_bf16_kernel<<<96, 256, 0, stream>>>(c0, cbuf, kB * kH);
  fill_kernel<<<49152, 256, 0, stream>>>(ys, kB * kS * kH);  // canary; scan overwrites all

  scan_kernel<<<192, 256, 0, stream>>>(Xb, hbuf, cbuf, Wall, Wallb, Uall, Uallb,
                                       Wd, Wdb, tsp, c0, ys, bar);
}

// Round 2
// 15389.780 us; speedup vs baseline: 1.6587x; 1.5116x over previous
//
#include <hip/hip_runtime.h>

static constexpr int kB = 128, kS = 512, kH = 768;

typedef __attribute__((ext_vector_type(8))) short short8;
typedef __attribute__((ext_vector_type(4))) float f32x4;

__device__ __forceinline__ unsigned short f2bf(float x) {
  unsigned u = __float_as_uint(x);
  u += 0x7fffu + ((u >> 16) & 1u);   // RNE
  return (unsigned short)(u >> 16);
}
__device__ __forceinline__ float bf2f(unsigned short h) {
  return __uint_as_float(((unsigned)h) << 16);
}
__device__ __forceinline__ short8 pack_bf8(const float* __restrict__ p) {
  short8 r;
#pragma unroll
  for (int i = 0; i < 8; ++i) r[i] = (short)f2bf(p[i]);
  return r;
}
__device__ __forceinline__ float fsigm(float x) {
  return __builtin_amdgcn_rcpf(1.0f + __expf(-x));
}
__device__ __forceinline__ float ftanh(float x) {
  return 1.0f - 2.0f * __builtin_amdgcn_rcpf(1.0f + __expf(2.0f * x));
}

// Coherent (LLC-direct) 16B load: two 8B agent-scope relaxed atomic loads.
// Bypasses L1/L2 so ping-pong h/c reads can never hit a stale line; compiler
// tracks the waitcnt. Only used for h/c; everything else stays cached.
__device__ __forceinline__ short8 ldg_agent16(const unsigned short* p) {
  union { unsigned long long q[2]; short8 v; } u;
  u.q[0] = __hip_atomic_load((const unsigned long long*)p + 0, __ATOMIC_RELAXED,
                             __HIP_MEMORY_SCOPE_AGENT);
  u.q[1] = __hip_atomic_load((const unsigned long long*)p + 1, __ATOMIC_RELAXED,
                             __HIP_MEMORY_SCOPE_AGENT);
  return u.v;
}
// Write-through (LLC-direct) packed 2xbf16 store.
__device__ __forceinline__ void st_agent4(unsigned short* p, unsigned short a,
                                          unsigned short b) {
  unsigned v = (unsigned)a | ((unsigned)b << 16);
  __hip_atomic_store((unsigned*)p, v, __ATOMIC_RELAXED, __HIP_MEMORY_SCOPE_AGENT);
}

// ---------------- fp32 -> bf16 cast (layout-preserving) ----------------
__global__ __launch_bounds__(256) void cast_bf16_kernel(const float* __restrict__ src,
                                                        unsigned short* __restrict__ dst,
                                                        int n) {
  int i = (blockIdx.x * 256 + threadIdx.x) * 4;
  if (i < n) {
    float4 v = *(const float4*)(src + i);
    *(ushort4*)(dst + i) = make_ushort4(f2bf(v.x), f2bf(v.y), f2bf(v.z), f2bf(v.w));
  }
}

// ---------------- fp32 [B][S][H] -> bf16 time-major [S][B][H] ----------------
__global__ __launch_bounds__(192) void cast_tr_kernel(const float* __restrict__ src,
                                                      unsigned short* __restrict__ dst) {
  const int bs = blockIdx.x;            // b*kS + s
  const int b = bs >> 9, s = bs & (kS - 1);
  const int i = threadIdx.x * 4;
  float4 v = *(const float4*)(src + (size_t)bs * kH + i);
  *(ushort4*)(dst + ((size_t)s * kB + b) * kH + i) =
      make_ushort4(f2bf(v.x), f2bf(v.y), f2bf(v.z), f2bf(v.w));
}

// ---------------- diagnostic canary: pre-fill ys ----------------
__global__ __launch_bounds__(256) void fill_kernel(float* __restrict__ p, int n) {
  int i = (blockIdx.x * 256 + threadIdx.x) * 4;
  if (i < n) *(float4*)(p + i) = make_float4(100.f, 100.f, 100.f, 100.f);
}

// ---------------- fence-free device-scope group barrier ----------------
// All shared state (h/c ping-pong, flags) moves via cache-bypassing agent-scope
// atomics, so no buffer_wbl2 / buffer_inv cache-wide fences are needed.
// __syncthreads() drains each wave's vmcnt before s_barrier (HW-verified compiler
// behavior), so every wave's write-through stores are LLC-visible before the
// flag store that follows. Explicit waitcnt kept as insurance.
__device__ __forceinline__ void group_barrier(unsigned* flags, int sid, unsigned target,
                                              int w, int lane) {
  asm volatile("s_waitcnt vmcnt(0)" ::: "memory");
  __syncthreads();
  if (threadIdx.x == 0)
    __hip_atomic_store(flags + sid * 16, target, __ATOMIC_RELAXED, __HIP_MEMORY_SCOPE_AGENT);
  if (w == 0) {
    const unsigned* p = flags + (lane < 48 ? lane : 0) * 16;
    for (;;) {
      unsigned v = __hip_atomic_load(p, __ATOMIC_RELAXED, __HIP_MEMORY_SCOPE_AGENT);
      if (__all(v >= target)) break;
      __builtin_amdgcn_s_sleep(1);
    }
  }
  __syncthreads();
}

// ---------------- the scan ----------------
// 192 blocks: g = bid&3 -> batch rows [g*32, +32); stripe = bid>>2 -> hidden cols [stripe*16, +16)
// wave w = gate w (f,i,o,c~) over 2 M-tiles; waves 0,1 additionally do the W_d GEMM
// for M-tile w. Weight B-frags are VGPR-resident (fully unrolled kk loop).
// h/c exchanged through global bf16 ping-pong buffers via LLC-direct atomics;
// c master copy is fp32 in LDS.
__global__ __launch_bounds__(256, 1) void scan_kernel(
    const unsigned short* __restrict__ Xb, unsigned short* __restrict__ hbuf,
    unsigned short* __restrict__ cbuf, const float* __restrict__ Wall,
    const float* __restrict__ Wallb, const float* __restrict__ Uall,
    const float* __restrict__ Uallb, const float* __restrict__ Wd,
    const float* __restrict__ Wdb, const float* __restrict__ ts,
    const float* __restrict__ c0, float* __restrict__ ys, unsigned* bar) {
  __shared__ float lds_pre[4][32][16];
  __shared__ float lds_d[32][16];
  __shared__ float lds_cm[32][16];

  const int t = threadIdx.x;
  const int w = t >> 6, lane = t & 63, l15 = lane & 15, lhi = lane >> 4;
  const int g = blockIdx.x & 3, stripe = blockIdx.x >> 2;
  const int b0 = g * 32, j0 = stripe * 16;
  unsigned* flags = bar + (size_t)g * 48 * 16;  // 48 slots, 64B apart, per group

  // step-invariant weights -> registers. B-frag: n=l15 (output col), k=lhi*8+j
  short8 wg[24], ug[24], wdv[24];
#pragma unroll
  for (int kk = 0; kk < 24; ++kk) {
    const float* wrow = Wall + (size_t)(w * kH + j0 + l15) * kH + kk * 32 + lhi * 8;
    const float* urow = Uall + (size_t)(w * kH + j0 + l15) * kH + kk * 32 + lhi * 8;
    wg[kk] = pack_bf8(wrow);
    ug[kk] = pack_bf8(urow);
  }
  const bool do_c = (w < 2);
  if (do_c) {
#pragma unroll
    for (int kk = 0; kk < 24; ++kk) {
      const float* drow = Wd + (size_t)(j0 + l15) * kH + kk * 32 + lhi * 8;
      wdv[kk] = pack_bf8(drow);
    }
  }

  // elementwise mapping: 32 rows x 8 thread-cols x 2 elems
  const int erow = t >> 3, eq = t & 7;
  const int eb = b0 + erow, jc = j0 + eq * 2;
  {
    float2 v = *(const float2*)(c0 + (size_t)eb * kH + jc);
    lds_cm[erow][eq * 2 + 0] = v.x;
    lds_cm[erow][eq * 2 + 1] = v.y;
  }
  float bsum[4][2], bd[2];
#pragma unroll
  for (int gg = 0; gg < 4; ++gg)
#pragma unroll
    for (int u = 0; u < 2; ++u) bsum[gg][u] = Wallb[gg * kH + jc + u] + Uallb[gg * kH + jc + u];
#pragma unroll
  for (int u = 0; u < 2; ++u) bd[u] = Wdb[jc + u];

  int hoff[2], xoff[2];
#pragma unroll
  for (int mt = 0; mt < 2; ++mt) {
    hoff[mt] = (b0 + mt * 16 + l15) * kH + lhi * 8;
    xoff[mt] = (b0 + mt * 16 + l15) * kH + lhi * 8;  // within time-major slab
  }
  const int coff = (b0 + (w & 1) * 16 + l15) * kH + lhi * 8;

  const float* tsrow = ts + (size_t)eb * kS;
  const size_t yrow = (size_t)eb * kS * kH + jc;

#pragma unroll 1
  for (int s = 0; s < kS; ++s) {
    const unsigned short* hb = hbuf + (s & 1) * (kB * kH);
    const unsigned short* cb = cbuf + (s & 1) * (kB * kH);
    unsigned short* hbn = hbuf + ((s + 1) & 1) * (kB * kH);
    unsigned short* cbn = cbuf + ((s + 1) & 1) * (kB * kH);
    const unsigned short* xs = Xb + (size_t)s * (kB * kH);  // contiguous 196KB slab

    const float tv = tsrow[s];  // issue early; overlaps MFMA loop

    // 5 independent accumulator chains for ILP
    f32x4 aw0 = {0.f, 0.f, 0.f, 0.f}, au0 = aw0, aw1 = aw0, au1 = aw0, ad = aw0;
#pragma unroll
    for (int kk = 0; kk < 24; ++kk) {
      const int o = kk * 32;
      short8 hf0 = ldg_agent16(hb + hoff[0] + o);
      aw0 = __builtin_amdgcn_mfma_f32_16x16x32_bf16(hf0, wg[kk], aw0, 0, 0, 0);
      short8 xf0 = *(const short8*)(xs + xoff[0] + o);
      au0 = __builtin_amdgcn_mfma_f32_16x16x32_bf16(xf0, ug[kk], au0, 0, 0, 0);
      short8 hf1 = ldg_agent16(hb + hoff[1] + o);
      aw1 = __builtin_amdgcn_mfma_f32_16x16x32_bf16(hf1, wg[kk], aw1, 0, 0, 0);
      short8 xf1 = *(const short8*)(xs + xoff[1] + o);
      au1 = __builtin_amdgcn_mfma_f32_16x16x32_bf16(xf1, ug[kk], au1, 0, 0, 0);
      if (do_c) {
        short8 cf = ldg_agent16(cb + coff + o);
        ad = __builtin_amdgcn_mfma_f32_16x16x32_bf16(cf, wdv[kk], ad, 0, 0, 0);
      }
    }
    // C/D layout: row = lhi*4+r, col = l15
#pragma unroll
    for (int r = 0; r < 4; ++r) {
      lds_pre[w][0 + lhi * 4 + r][l15] = aw0[r] + au0[r];
      lds_pre[w][16 + lhi * 4 + r][l15] = aw1[r] + au1[r];
    }
    if (do_c) {
#pragma unroll
      for (int r = 0; r < 4; ++r) lds_d[w * 16 + lhi * 4 + r][l15] = ad[r];
    }
    __syncthreads();

    float hn[2], cn[2];
#pragma unroll
    for (int u = 0; u < 2; ++u) {
      const int jj = eq * 2 + u;
      float cs1 = ftanh(lds_d[erow][jj] + bd[u]);
      float cold = lds_cm[erow][jj];
      float cadj = cold + cs1 * (tv - 1.0f);  // (c - cs1) + cs1*t
      float fv = fsigm(lds_pre[0][erow][jj] + bsum[0][u]);
      float iv = fsigm(lds_pre[1][erow][jj] + bsum[1][u]);
      float ov = fsigm(lds_pre[2][erow][jj] + bsum[2][u]);
      float cv = fsigm(lds_pre[3][erow][jj] + bsum[3][u]);
      float cnew = fv * cadj + iv * cv;
      float hnew = ov * ftanh(cnew);
      lds_cm[erow][jj] = cnew;
      hn[u] = hnew;
      cn[u] = cnew;
    }
    *(float2*)(ys + yrow + (size_t)s * kH) = make_float2(hn[0], hn[1]);
    st_agent4(hbn + eb * kH + jc, f2bf(hn[0]), f2bf(hn[1]));
    st_agent4(cbn + eb * kH + jc, f2bf(cn[0]), f2bf(cn[1]));

    if (s != kS - 1) group_barrier(flags, stripe, (unsigned)(s + 1), w, lane);
  }
}

extern "C" void kernel_launch(void* const* d_in, const int* in_sizes, int n_in,
                              void* d_out, int out_size, void* d_ws, size_t ws_size,
                              hipStream_t stream) {
  const float* inputs = (const float*)d_in[0];
  const float* tsp    = (const float*)d_in[1];
  const float* h0     = (const float*)d_in[2];
  const float* c0     = (const float*)d_in[3];
  const float* Wall   = (const float*)d_in[4];
  const float* Wallb  = (const float*)d_in[5];
  const float* Uall   = (const float*)d_in[6];
  const float* Uallb  = (const float*)d_in[7];
  const float* Wd     = (const float*)d_in[8];
  const float* Wdb    = (const float*)d_in[9];
  float* ys = (float*)d_out;

  char* ws = (char*)d_ws;
  unsigned* bar        = (unsigned*)(ws);                 // 16 KB (4 groups x 48 flags, 64B apart)
  unsigned short* hbuf = (unsigned short*)(ws + 16384);   // 393,216 B (ping-pong)
  unsigned short* cbuf = (unsigned short*)(ws + 409600);  // 393,216 B (ping-pong)
  unsigned short* Xb   = (unsigned short*)(ws + 802816);  // 100,663,296 B (time-major)

  hipMemsetAsync(bar, 0, 16384, stream);
  cast_tr_kernel<<<kB * kS, 192, 0, stream>>>(inputs, Xb);
  cast_bf16_kernel<<<96, 256, 0, stream>>>(h0, hbuf, kB * kH);
  cast_bf16_kernel<<<96, 256, 0, stream>>>(c0, cbuf, kB * kH);
  fill_kernel<<<49152, 256, 0, stream>>>(ys, kB * kS * kH);  // canary; scan overwrites all

  scan_kernel<<<192, 256, 0, stream>>>(Xb, hbuf, cbuf, Wall, Wallb, Uall, Uallb,
                                       Wd, Wdb, tsp, c0, ys, bar);
}

// Round 3
// 12929.037 us; speedup vs baseline: 1.9743x; 1.1903x over previous
//
#include <hip/hip_runtime.h>

static constexpr int kB = 128, kS = 512, kH = 768;

typedef __attribute__((ext_vector_type(8))) short short8;
typedef __attribute__((ext_vector_type(4))) float f32x4;

__device__ __forceinline__ unsigned short f2bf(float x) {
  unsigned u = __float_as_uint(x);
  u += 0x7fffu + ((u >> 16) & 1u);   // RNE
  return (unsigned short)(u >> 16);
}
__device__ __forceinline__ short8 pack_bf8(const float* __restrict__ p) {
  short8 r;
#pragma unroll
  for (int i = 0; i < 8; ++i) r[i] = (short)f2bf(p[i]);
  return r;
}
__device__ __forceinline__ float fsigm(float x) {
  return __builtin_amdgcn_rcpf(1.0f + __expf(-x));
}
__device__ __forceinline__ float ftanh(float x) {
  return 1.0f - 2.0f * __builtin_amdgcn_rcpf(1.0f + __expf(2.0f * x));
}

// Coherent (LLC-direct) 16B load: two 8B agent-scope relaxed atomic loads.
// Bypasses L1/L2 so ping-pong h/c reads can never hit a stale line.
__device__ __forceinline__ short8 ldg_agent16(const unsigned short* p) {
  union { unsigned long long q[2]; short8 v; } u;
  u.q[0] = __hip_atomic_load((const unsigned long long*)p + 0, __ATOMIC_RELAXED,
                             __HIP_MEMORY_SCOPE_AGENT);
  u.q[1] = __hip_atomic_load((const unsigned long long*)p + 1, __ATOMIC_RELAXED,
                             __HIP_MEMORY_SCOPE_AGENT);
  return u.v;
}
// Write-through (LLC-direct) packed 2xbf16 store.
__device__ __forceinline__ void st_agent4(unsigned short* p, unsigned short a,
                                          unsigned short b) {
  unsigned v = (unsigned)a | ((unsigned)b << 16);
  __hip_atomic_store((unsigned*)p, v, __ATOMIC_RELAXED, __HIP_MEMORY_SCOPE_AGENT);
}

// ---------------- fp32 -> bf16 cast (layout-preserving) ----------------
__global__ __launch_bounds__(256) void cast_bf16_kernel(const float* __restrict__ src,
                                                        unsigned short* __restrict__ dst,
                                                        int n) {
  int i = (blockIdx.x * 256 + threadIdx.x) * 4;
  if (i < n) {
    float4 v = *(const float4*)(src + i);
    *(ushort4*)(dst + i) = make_ushort4(f2bf(v.x), f2bf(v.y), f2bf(v.z), f2bf(v.w));
  }
}

// ---------------- fp32 [B][S][H] -> bf16 time-major [S][B][H] ----------------
__global__ __launch_bounds__(192) void cast_tr_kernel(const float* __restrict__ src,
                                                      unsigned short* __restrict__ dst) {
  const int bs = blockIdx.x;            // b*kS + s
  const int b = bs >> 9, s = bs & (kS - 1);
  const int i = threadIdx.x * 4;
  float4 v = *(const float4*)(src + (size_t)bs * kH + i);
  *(ushort4*)(dst + ((size_t)s * kB + b) * kH + i) =
      make_ushort4(f2bf(v.x), f2bf(v.y), f2bf(v.z), f2bf(v.w));
}

// ---------------- diagnostic canary: pre-fill ys ----------------
__global__ __launch_bounds__(256) void fill_kernel(float* __restrict__ p, int n) {
  int i = (blockIdx.x * 256 + threadIdx.x) * 4;
  if (i < n) *(float4*)(p + i) = make_float4(100.f, 100.f, 100.f, 100.f);
}

// ---------------- fence-free device-scope group barrier (epoch-aggregated) ----
// Arrival: one relaxed agent store per block to its own 64B-spaced flag slot.
// Aggregation: block stripe==0's wave 0 gathers all 48 flags (one 48-lane load
// per iteration) and publishes a single per-group epoch word. All other blocks
// poll ONLY that one cacheline (64-lane same-address load = 1 LLC transaction),
// cutting poll traffic ~48x. LLC is the single coherence point, so
// flags-at-LLC -> epoch-at-LLC -> consumer load gives transitive visibility of
// all data stores that preceded each flag (each wave drains vmcnt before
// __syncthreads, and the flag store is issued after the barrier).
__device__ __forceinline__ void group_barrier(unsigned* flags, int stripe,
                                              unsigned target, int w, int lane) {
  asm volatile("s_waitcnt vmcnt(0)" ::: "memory");
  __syncthreads();
  if (threadIdx.x == 0)
    __hip_atomic_store(flags + stripe * 16, target, __ATOMIC_RELAXED,
                       __HIP_MEMORY_SCOPE_AGENT);
  if (w == 0) {
    if (stripe == 0) {
      const unsigned* p = flags + (lane < 48 ? lane : 0) * 16;
      for (;;) {
        unsigned v = __hip_atomic_load(p, __ATOMIC_RELAXED, __HIP_MEMORY_SCOPE_AGENT);
        if (__all(v >= target)) break;
        __builtin_amdgcn_s_sleep(1);
      }
      if (lane == 0)
        __hip_atomic_store(flags + 63 * 16, target, __ATOMIC_RELAXED,
                           __HIP_MEMORY_SCOPE_AGENT);
    } else {
      const unsigned* p = flags + 63 * 16;
      for (;;) {
        unsigned v = __hip_atomic_load(p, __ATOMIC_RELAXED, __HIP_MEMORY_SCOPE_AGENT);
        if (__all(v >= target)) break;
      }
    }
  }
  __syncthreads();
}

// ---------------- the scan ----------------
// 192 blocks: g = bid&3 -> batch rows [g*32, +32); stripe = bid>>2 -> hidden cols
// [stripe*16, +16). wave w = gate w (f,i,o,c~) over 2 M-tiles; waves 0,1 also do
// the W_d GEMM for M-tile w. Weight B-frags are VGPR-resident. h is staged ONCE
// per block per step into LDS (padded, conflict-free) instead of 4x-redundant
// LLC-direct loads; c ping-pong reads stay LLC-direct (already 1x-unique).
// c master copy lives in 2 registers per thread (each (row,col) owned by exactly
// one thread).
__global__ __launch_bounds__(256, 1) void scan_kernel(
    const unsigned short* __restrict__ Xb, unsigned short* __restrict__ hbuf,
    unsigned short* __restrict__ cbuf, const float* __restrict__ Wall,
    const float* __restrict__ Wallb, const float* __restrict__ Uall,
    const float* __restrict__ Uallb, const float* __restrict__ Wd,
    const float* __restrict__ Wdb, const float* __restrict__ ts,
    const float* __restrict__ c0, float* __restrict__ ys, unsigned* bar) {
  // row stride 776 shorts = 1552B = 97 x 16B (odd) -> ds_read/write_b128 at
  // structural-minimum bank usage (16B-group = (row + col16) & 7).
  __shared__ unsigned short lds_h[32][776];   // 49,664 B
  __shared__ float lds_pre[4][32][16];        //  8,192 B
  __shared__ float lds_d[32][16];             //  2,048 B

  const int t = threadIdx.x;
  const int w = t >> 6, lane = t & 63, l15 = lane & 15, lhi = lane >> 4;
  const int g = blockIdx.x & 3, stripe = blockIdx.x >> 2;
  const int b0 = g * 32, j0 = stripe * 16;
  unsigned* flags = bar + (size_t)g * 1024;  // 4KB per group: 48 flags + epoch@63

  // step-invariant weights -> registers. B-frag: n=l15 (output col), k=lhi*8+j
  short8 wg[24], ug[24], wdv[24];
#pragma unroll
  for (int kk = 0; kk < 24; ++kk) {
    const float* wrow = Wall + (size_t)(w * kH + j0 + l15) * kH + kk * 32 + lhi * 8;
    const float* urow = Uall + (size_t)(w * kH + j0 + l15) * kH + kk * 32 + lhi * 8;
    wg[kk] = pack_bf8(wrow);
    ug[kk] = pack_bf8(urow);
  }
  const bool do_c = (w < 2);
  if (do_c) {
#pragma unroll
    for (int kk = 0; kk < 24; ++kk) {
      const float* drow = Wd + (size_t)(j0 + l15) * kH + kk * 32 + lhi * 8;
      wdv[kk] = pack_bf8(drow);
    }
  }

  // elementwise mapping: 32 rows x 8 thread-cols x 2 elems
  const int erow = t >> 3, eq = t & 7;
  const int eb = b0 + erow, jc = j0 + eq * 2;
  float cm[2];  // fp32 master copy of this thread's two c elements
  {
    float2 v = *(const float2*)(c0 + (size_t)eb * kH + jc);
    cm[0] = v.x;
    cm[1] = v.y;
  }
  float bsum[4][2], bd[2];
#pragma unroll
  for (int gg = 0; gg < 4; ++gg)
#pragma unroll
    for (int u = 0; u < 2; ++u) bsum[gg][u] = Wallb[gg * kH + jc + u] + Uallb[gg * kH + jc + u];
#pragma unroll
  for (int u = 0; u < 2; ++u) bd[u] = Wdb[jc + u];

  int xoff[2];
#pragma unroll
  for (int mt = 0; mt < 2; ++mt) xoff[mt] = (b0 + mt * 16 + l15) * kH + lhi * 8;
  const int coff = (b0 + (w & 1) * 16 + l15) * kH + lhi * 8;

  // h staging mapping: thread (srow = t>>3, sin = t&7) stages row srow,
  // 16B chunks sin + 8j, j = 0..11 (96 chunks per 1536B row).
  const int srow = t >> 3, sin = t & 7;

  const float* tsrow = ts + (size_t)eb * kS;
  const size_t yrow = (size_t)eb * kS * kH + jc;

#pragma unroll 1
  for (int s = 0; s < kS; ++s) {
    const unsigned short* hb = hbuf + (s & 1) * (kB * kH);
    const unsigned short* cb = cbuf + (s & 1) * (kB * kH);
    unsigned short* hbn = hbuf + ((s + 1) & 1) * (kB * kH);
    unsigned short* cbn = cbuf + ((s + 1) & 1) * (kB * kH);
    const unsigned short* xs = Xb + (size_t)s * (kB * kH);  // contiguous 196KB slab

    // ---- stage h (48KB unique) once into LDS via coherent loads ----
    {
      const unsigned short* hrow = hb + (size_t)(b0 + srow) * kH;
#pragma unroll
      for (int j = 0; j < 12; ++j) {
        const int c8 = sin + j * 8;
        union { unsigned long long q[2]; short8 v; } u;
        const unsigned long long* gp = (const unsigned long long*)(hrow + c8 * 8);
        u.q[0] = __hip_atomic_load(gp + 0, __ATOMIC_RELAXED, __HIP_MEMORY_SCOPE_AGENT);
        u.q[1] = __hip_atomic_load(gp + 1, __ATOMIC_RELAXED, __HIP_MEMORY_SCOPE_AGENT);
        *(short8*)&lds_h[srow][c8 * 8] = u.v;
      }
    }
    const float tv = tsrow[s];  // overlaps staging latency
    __syncthreads();

    // ---- GEMMs: h@W^T (LDS), x@U^T (cached), c@Wd^T (LLC-direct) ----
    f32x4 aw0 = {0.f, 0.f, 0.f, 0.f}, au0 = aw0, aw1 = aw0, au1 = aw0, ad = aw0;
#pragma unroll
    for (int kk = 0; kk < 24; ++kk) {
      const int o = kk * 32;
      short8 hf0 = *(const short8*)&lds_h[l15][o + lhi * 8];
      aw0 = __builtin_amdgcn_mfma_f32_16x16x32_bf16(hf0, wg[kk], aw0, 0, 0, 0);
      short8 xf0 = *(const short8*)(xs + xoff[0] + o);
      au0 = __builtin_amdgcn_mfma_f32_16x16x32_bf16(xf0, ug[kk], au0, 0, 0, 0);
      short8 hf1 = *(const short8*)&lds_h[16 + l15][o + lhi * 8];
      aw1 = __builtin_amdgcn_mfma_f32_16x16x32_bf16(hf1, wg[kk], aw1, 0, 0, 0);
      short8 xf1 = *(const short8*)(xs + xoff[1] + o);
      au1 = __builtin_amdgcn_mfma_f32_16x16x32_bf16(xf1, ug[kk], au1, 0, 0, 0);
      if (do_c) {
        short8 cf = ldg_agent16(cb + coff + o);
        ad = __builtin_amdgcn_mfma_f32_16x16x32_bf16(cf, wdv[kk], ad, 0, 0, 0);
      }
    }
    // C/D layout: row = lhi*4+r, col = l15
#pragma unroll
    for (int r = 0; r < 4; ++r) {
      lds_pre[w][0 + lhi * 4 + r][l15] = aw0[r] + au0[r];
      lds_pre[w][16 + lhi * 4 + r][l15] = aw1[r] + au1[r];
    }
    if (do_c) {
#pragma unroll
      for (int r = 0; r < 4; ++r) lds_d[w * 16 + lhi * 4 + r][l15] = ad[r];
    }
    __syncthreads();

    float hn[2], cn[2];
#pragma unroll
    for (int u = 0; u < 2; ++u) {
      const int jj = eq * 2 + u;
      float cs1 = ftanh(lds_d[erow][jj] + bd[u]);
      float cadj = cm[u] + cs1 * (tv - 1.0f);  // (c - cs1) + cs1*t
      float fv = fsigm(lds_pre[0][erow][jj] + bsum[0][u]);
      float iv = fsigm(lds_pre[1][erow][jj] + bsum[1][u]);
      float ov = fsigm(lds_pre[2][erow][jj] + bsum[2][u]);
      float cv = fsigm(lds_pre[3][erow][jj] + bsum[3][u]);
      float cnew = fv * cadj + iv * cv;
      float hnew = ov * ftanh(cnew);
      cm[u] = cnew;
      hn[u] = hnew;
      cn[u] = cnew;
    }
    *(float2*)(ys + yrow + (size_t)s * kH) = make_float2(hn[0], hn[1]);
    st_agent4(hbn + eb * kH + jc, f2bf(hn[0]), f2bf(hn[1]));
    st_agent4(cbn + eb * kH + jc, f2bf(cn[0]), f2bf(cn[1]));

    if (s != kS - 1) group_barrier(flags, stripe, (unsigned)(s + 1), w, lane);
  }
}

extern "C" void kernel_launch(void* const* d_in, const int* in_sizes, int n_in,
                              void* d_out, int out_size, void* d_ws, size_t ws_size,
                              hipStream_t stream) {
  const float* inputs = (const float*)d_in[0];
  const float* tsp    = (const float*)d_in[1];
  const float* h0     = (const float*)d_in[2];
  const float* c0     = (const float*)d_in[3];
  const float* Wall   = (const float*)d_in[4];
  const float* Wallb  = (const float*)d_in[5];
  const float* Uall   = (const float*)d_in[6];
  const float* Uallb  = (const float*)d_in[7];
  const float* Wd     = (const float*)d_in[8];
  const float* Wdb    = (const float*)d_in[9];
  float* ys = (float*)d_out;

  char* ws = (char*)d_ws;
  unsigned* bar        = (unsigned*)(ws);                 // 16 KB (4 groups x 4KB: flags + epoch)
  unsigned short* hbuf = (unsigned short*)(ws + 16384);   // 393,216 B (ping-pong)
  unsigned short* cbuf = (unsigned short*)(ws + 409600);  // 393,216 B (ping-pong)
  unsigned short* Xb   = (unsigned short*)(ws + 802816);  // 100,663,296 B (time-major)

  hipMemsetAsync(bar, 0, 16384, stream);
  cast_tr_kernel<<<kB * kS, 192, 0, stream>>>(inputs, Xb);
  cast_bf16_kernel<<<96, 256, 0, stream>>>(h0, hbuf, kB * kH);
  cast_bf16_kernel<<<96, 256, 0, stream>>>(c0, cbuf, kB * kH);
  fill_kernel<<<49152, 256, 0, stream>>>(ys, kB * kS * kH);  // canary; scan overwrites all

  scan_kernel<<<192, 256, 0, stream>>>(Xb, hbuf, cbuf, Wall, Wallb, Uall, Uallb,
                                       Wd, Wdb, tsp, c0, ys, bar);
}

// Round 4
// 10043.836 us; speedup vs baseline: 2.5415x; 1.2873x over previous
//
#include <hip/hip_runtime.h>

static constexpr int kB = 128, kS = 512, kH = 768;

typedef __attribute__((ext_vector_type(8))) short short8;
typedef __attribute__((ext_vector_type(4))) float f32x4;

__device__ __forceinline__ unsigned short f2bf(float x) {
  unsigned u = __float_as_uint(x);
  u += 0x7fffu + ((u >> 16) & 1u);   // RNE
  return (unsigned short)(u >> 16);
}
__device__ __forceinline__ short8 pack_bf8(const float* __restrict__ p) {
  short8 r;
#pragma unroll
  for (int i = 0; i < 8; ++i) r[i] = (short)f2bf(p[i]);
  return r;
}
__device__ __forceinline__ float fsigm(float x) {
  return __builtin_amdgcn_rcpf(1.0f + __expf(-x));
}
__device__ __forceinline__ float ftanh(float x) {
  return 1.0f - 2.0f * __builtin_amdgcn_rcpf(1.0f + __expf(2.0f * x));
}

// Coherent (LLC-direct) 16B load: two 8B agent-scope relaxed atomic loads.
__device__ __forceinline__ short8 ldg_agent16(const unsigned short* p) {
  union { unsigned long long q[2]; short8 v; } u;
  u.q[0] = __hip_atomic_load((const unsigned long long*)p + 0, __ATOMIC_RELAXED,
                             __HIP_MEMORY_SCOPE_AGENT);
  u.q[1] = __hip_atomic_load((const unsigned long long*)p + 1, __ATOMIC_RELAXED,
                             __HIP_MEMORY_SCOPE_AGENT);
  return u.v;
}
// Write-through (LLC-direct) packed 2xbf16 store.
__device__ __forceinline__ void st_agent4(unsigned short* p, unsigned short a,
                                          unsigned short b) {
  unsigned v = (unsigned)a | ((unsigned)b << 16);
  __hip_atomic_store((unsigned*)p, v, __ATOMIC_RELAXED, __HIP_MEMORY_SCOPE_AGENT);
}

// ---------------- fp32 -> bf16 cast (layout-preserving) ----------------
__global__ __launch_bounds__(256) void cast_bf16_kernel(const float* __restrict__ src,
                                                        unsigned short* __restrict__ dst,
                                                        int n) {
  int i = (blockIdx.x * 256 + threadIdx.x) * 4;
  if (i < n) {
    float4 v = *(const float4*)(src + i);
    *(ushort4*)(dst + i) = make_ushort4(f2bf(v.x), f2bf(v.y), f2bf(v.z), f2bf(v.w));
  }
}

// ---------------- fp32 [B][S][H] -> bf16 time-major [S][B][H] ----------------
__global__ __launch_bounds__(192) void cast_tr_kernel(const float* __restrict__ src,
                                                      unsigned short* __restrict__ dst) {
  const int bs = blockIdx.x;            // b*kS + s
  const int b = bs >> 9, s = bs & (kS - 1);
  const int i = threadIdx.x * 4;
  float4 v = *(const float4*)(src + (size_t)bs * kH + i);
  *(ushort4*)(dst + ((size_t)s * kB + b) * kH + i) =
      make_ushort4(f2bf(v.x), f2bf(v.y), f2bf(v.z), f2bf(v.w));
}

// ---------------- diagnostic canary: pre-fill ys ----------------
__global__ __launch_bounds__(256) void fill_kernel(float* __restrict__ p, int n) {
  int i = (blockIdx.x * 256 + threadIdx.x) * 4;
  if (i < n) *(float4*)(p + i) = make_float4(100.f, 100.f, 100.f, 100.f);
}

// ---------------- the scan ----------------
// 192 blocks: g = bid&3 -> batch rows [g*32, +32); stripe = bid>>2 -> hidden cols
// [stripe*16, +16). wave w = gate w (f,i,o,c~) over 2 M-tiles; waves 0,1 also do
// the W_d GEMM for M-tile w. W/U B-frags VGPR-resident; Wd B-frags in LDS
// (identical for waves 0/1 -> written once, removes register spills).
// h AND c staged once per block per step into LDS via one pipelined coherent
// burst (24 x 16B per thread); MFMA loop touches only LDS + cached X.
// c master copy lives in 2 fp32 registers per owning thread.
__global__ __launch_bounds__(256, 1) void scan_kernel(
    const unsigned short* __restrict__ Xb, unsigned short* __restrict__ hbuf,
    unsigned short* __restrict__ cbuf, const float* __restrict__ Wall,
    const float* __restrict__ Wallb, const float* __restrict__ Uall,
    const float* __restrict__ Uallb, const float* __restrict__ Wd,
    const float* __restrict__ Wdb, const float* __restrict__ ts,
    const float* __restrict__ c0, float* __restrict__ ys, unsigned* bar) {
  // row stride 776 shorts = 1552B = 97 x 16B (odd) -> near-minimal bank clash.
  __shared__ unsigned short lds_h[32][776];   // 49,664 B
  __shared__ unsigned short lds_c[32][776];   // 49,664 B
  __shared__ short8 lds_wd[24][64];           // 24,576 B
  __shared__ float lds_pre[4][32][16];        //  8,192 B
  __shared__ float lds_d[32][16];             //  2,048 B  (total 134,144 B)

  const int t = threadIdx.x;
  const int w = t >> 6, lane = t & 63, l15 = lane & 15, lhi = lane >> 4;
  const int g = blockIdx.x & 3, stripe = blockIdx.x >> 2;
  const int b0 = g * 32, j0 = stripe * 16;
  unsigned* flags = bar + (size_t)g * 1024;  // 4KB per group: 48 flags + epoch@63

  // step-invariant W/U weights -> registers. B-frag: n=l15, k=lhi*8+j
  short8 wg[24], ug[24];
#pragma unroll
  for (int kk = 0; kk < 24; ++kk) {
    const float* wrow = Wall + (size_t)(w * kH + j0 + l15) * kH + kk * 32 + lhi * 8;
    const float* urow = Uall + (size_t)(w * kH + j0 + l15) * kH + kk * 32 + lhi * 8;
    wg[kk] = pack_bf8(wrow);
    ug[kk] = pack_bf8(urow);
  }
  // Wd fragments: identical for waves 0 and 1 -> LDS, written by wave 0.
  if (w == 0) {
#pragma unroll
    for (int kk = 0; kk < 24; ++kk) {
      const float* drow = Wd + (size_t)(j0 + l15) * kH + kk * 32 + lhi * 8;
      lds_wd[kk][lane] = pack_bf8(drow);
    }
  }
  const bool do_c = (w < 2);

  // elementwise mapping: 32 rows x 8 thread-cols x 2 elems
  const int erow = t >> 3, eq = t & 7;
  const int eb = b0 + erow, jc = j0 + eq * 2;
  float cm[2];  // fp32 master copy of this thread's two c elements
  {
    float2 v = *(const float2*)(c0 + (size_t)eb * kH + jc);
    cm[0] = v.x;
    cm[1] = v.y;
  }
  float bsum[4][2], bd[2];
#pragma unroll
  for (int gg = 0; gg < 4; ++gg)
#pragma unroll
    for (int u = 0; u < 2; ++u) bsum[gg][u] = Wallb[gg * kH + jc + u] + Uallb[gg * kH + jc + u];
#pragma unroll
  for (int u = 0; u < 2; ++u) bd[u] = Wdb[jc + u];

  int xoff[2];
#pragma unroll
  for (int mt = 0; mt < 2; ++mt) xoff[mt] = (b0 + mt * 16 + l15) * kH + lhi * 8;

  // staging mapping: thread (srow = t>>3, sin = t&7) stages row srow,
  // 16B chunks sin + 8j, j = 0..11 (96 chunks per 1536B row), for h and c.
  const int srow = t >> 3, sin = t & 7;

  const float* tsrow = ts + (size_t)eb * kS;
  const size_t yrow = (size_t)eb * kS * kH + jc;
  __syncthreads();  // lds_wd ready

#pragma unroll 1
  for (int s = 0; s < kS; ++s) {
    const unsigned short* hb = hbuf + (s & 1) * (kB * kH);
    const unsigned short* cb = cbuf + (s & 1) * (kB * kH);
    unsigned short* hbn = hbuf + ((s + 1) & 1) * (kB * kH);
    unsigned short* cbn = cbuf + ((s + 1) & 1) * (kB * kH);
    const unsigned short* xs = Xb + (size_t)s * (kB * kH);  // contiguous 196KB slab

    // ---- stage h + c (96KB unique) once into LDS: one pipelined burst ----
    {
      const unsigned short* hrow = hb + (size_t)(b0 + srow) * kH;
      const unsigned short* crow = cb + (size_t)(b0 + srow) * kH;
#pragma unroll
      for (int j = 0; j < 12; ++j) {
        const int c8 = sin + j * 8;
        *(short8*)&lds_h[srow][c8 * 8] = ldg_agent16(hrow + c8 * 8);
      }
#pragma unroll
      for (int j = 0; j < 12; ++j) {
        const int c8 = sin + j * 8;
        *(short8*)&lds_c[srow][c8 * 8] = ldg_agent16(crow + c8 * 8);
      }
    }
    const float tv = tsrow[s];  // overlaps staging latency
    __syncthreads();

    // ---- GEMMs: h@W^T (LDS), x@U^T (cached), c@Wd^T (LDS) ----
    f32x4 aw0 = {0.f, 0.f, 0.f, 0.f}, au0 = aw0, aw1 = aw0, au1 = aw0, ad = aw0;
#pragma unroll
    for (int kk = 0; kk < 24; ++kk) {
      const int o = kk * 32;
      short8 hf0 = *(const short8*)&lds_h[l15][o + lhi * 8];
      aw0 = __builtin_amdgcn_mfma_f32_16x16x32_bf16(hf0, wg[kk], aw0, 0, 0, 0);
      short8 xf0 = *(const short8*)(xs + xoff[0] + o);
      au0 = __builtin_amdgcn_mfma_f32_16x16x32_bf16(xf0, ug[kk], au0, 0, 0, 0);
      short8 hf1 = *(const short8*)&lds_h[16 + l15][o + lhi * 8];
      aw1 = __builtin_amdgcn_mfma_f32_16x16x32_bf16(hf1, wg[kk], aw1, 0, 0, 0);
      short8 xf1 = *(const short8*)(xs + xoff[1] + o);
      au1 = __builtin_amdgcn_mfma_f32_16x16x32_bf16(xf1, ug[kk], au1, 0, 0, 0);
      if (do_c) {
        short8 cf = *(const short8*)&lds_c[(w & 1) * 16 + l15][o + lhi * 8];
        ad = __builtin_amdgcn_mfma_f32_16x16x32_bf16(cf, lds_wd[kk][lane], ad, 0, 0, 0);
      }
    }
    // C/D layout: row = lhi*4+r, col = l15
#pragma unroll
    for (int r = 0; r < 4; ++r) {
      lds_pre[w][0 + lhi * 4 + r][l15] = aw0[r] + au0[r];
      lds_pre[w][16 + lhi * 4 + r][l15] = aw1[r] + au1[r];
    }
    if (do_c) {
#pragma unroll
      for (int r = 0; r < 4; ++r) lds_d[w * 16 + lhi * 4 + r][l15] = ad[r];
    }
    __syncthreads();

    float hn[2], cn[2];
#pragma unroll
    for (int u = 0; u < 2; ++u) {
      const int jj = eq * 2 + u;
      float cs1 = ftanh(lds_d[erow][jj] + bd[u]);
      float cadj = cm[u] + cs1 * (tv - 1.0f);  // (c - cs1) + cs1*t
      float fv = fsigm(lds_pre[0][erow][jj] + bsum[0][u]);
      float iv = fsigm(lds_pre[1][erow][jj] + bsum[1][u]);
      float ov = fsigm(lds_pre[2][erow][jj] + bsum[2][u]);
      float cv = fsigm(lds_pre[3][erow][jj] + bsum[3][u]);
      float cnew = fv * cadj + iv * cv;
      float hnew = ov * ftanh(cnew);
      cm[u] = cnew;
      hn[u] = hnew;
      cn[u] = cnew;
    }
    st_agent4(hbn + eb * kH + jc, f2bf(hn[0]), f2bf(hn[1]));
    st_agent4(cbn + eb * kH + jc, f2bf(cn[0]), f2bf(cn[1]));

    if (s != kS - 1) {
      // arrive: drain h/c write-through stores, then publish flag
      asm volatile("s_waitcnt vmcnt(0)" ::: "memory");
      __syncthreads();
      if (threadIdx.x == 0)
        __hip_atomic_store(flags + stripe * 16, (unsigned)(s + 1), __ATOMIC_RELAXED,
                           __HIP_MEMORY_SCOPE_AGENT);
      // ys store off the critical path (drained by next step's vmcnt(0))
      *(float2*)(ys + yrow + (size_t)s * kH) = make_float2(hn[0], hn[1]);
      // wait: stripe 0 aggregates 48 flags -> epoch; others poll epoch only
      const unsigned target = (unsigned)(s + 1);
      if (w == 0) {
        if (stripe == 0) {
          const unsigned* p = flags + (lane < 48 ? lane : 0) * 16;
          for (;;) {
            unsigned v = __hip_atomic_load(p, __ATOMIC_RELAXED, __HIP_MEMORY_SCOPE_AGENT);
            if (__all(v >= target)) break;
            __builtin_amdgcn_s_sleep(1);
          }
          if (lane == 0)
            __hip_atomic_store(flags + 63 * 16, target, __ATOMIC_RELAXED,
                               __HIP_MEMORY_SCOPE_AGENT);
        } else {
          const unsigned* p = flags + 63 * 16;
          for (;;) {
            unsigned v = __hip_atomic_load(p, __ATOMIC_RELAXED, __HIP_MEMORY_SCOPE_AGENT);
            if (__all(v >= target)) break;
          }
        }
      }
      __syncthreads();
    } else {
      *(float2*)(ys + yrow + (size_t)s * kH) = make_float2(hn[0], hn[1]);
    }
  }
}

extern "C" void kernel_launch(void* const* d_in, const int* in_sizes, int n_in,
                              void* d_out, int out_size, void* d_ws, size_t ws_size,
                              hipStream_t stream) {
  const float* inputs = (const float*)d_in[0];
  const float* tsp    = (const float*)d_in[1];
  const float* h0     = (const float*)d_in[2];
  const float* c0     = (const float*)d_in[3];
  const float* Wall   = (const float*)d_in[4];
  const float* Wallb  = (const float*)d_in[5];
  const float* Uall   = (const float*)d_in[6];
  const float* Uallb  = (const float*)d_in[7];
  const float* Wd     = (const float*)d_in[8];
  const float* Wdb    = (const float*)d_in[9];
  float* ys = (float*)d_out;

  char* ws = (char*)d_ws;
  unsigned* bar        = (unsigned*)(ws);                 // 16 KB (4 groups x 4KB: flags + epoch)
  unsigned short* hbuf = (unsigned short*)(ws + 16384);   // 393,216 B (ping-pong)
  unsigned short* cbuf = (unsigned short*)(ws + 409600);  // 393,216 B (ping-pong)
  unsigned short* Xb   = (unsigned short*)(ws + 802816);  // 100,663,296 B (time-major)

  hipMemsetAsync(bar, 0, 16384, stream);
  cast_tr_kernel<<<kB * kS, 192, 0, stream>>>(inputs, Xb);
  cast_bf16_kernel<<<96, 256, 0, stream>>>(h0, hbuf, kB * kH);
  cast_bf16_kernel<<<96, 256, 0, stream>>>(c0, cbuf, kB * kH);
  fill_kernel<<<49152, 256, 0, stream>>>(ys, kB * kS * kH);  // canary; scan overwrites all

  scan_kernel<<<192, 256, 0, stream>>>(Xb, hbuf, cbuf, Wall, Wallb, Uall, Uallb,
                                       Wd, Wdb, tsp, c0, ys, bar);
}